// Round 1
// baseline (406.990 us; speedup 1.0000x reference)
//
#include <hip/hip_runtime.h>
#include <hip/hip_bf16.h>
#include <math.h>

// FMFFN: x(8,64,256,256) -> 1x1conv(64->256) -> exact GELU -> 1x1conv(256->64)
//        -> per-channel 4x4-window spectral filter (== circular conv, see setup_ker)
// Fused bf16-MFMA kernel, wave-autonomous (no block barriers).

typedef __attribute__((ext_vector_type(8))) short short8;
typedef __attribute__((ext_vector_type(4))) float floatx4;

__device__ __forceinline__ unsigned short f2b_rne(float f) {
  unsigned u = __builtin_bit_cast(unsigned, f);
  u += 0x7fffu + ((u >> 16) & 1u);
  return (unsigned short)(u >> 16);
}

// ---- setup: cast w1 (256x64) and w2 (64x256) to bf16 (same layout = B^T form) ----
__global__ void setup_weights(const float* __restrict__ w1, const float* __restrict__ w2,
                              unsigned short* __restrict__ w1b, unsigned short* __restrict__ w2b) {
  int t = blockIdx.x * 256 + threadIdx.x;  // 0..32767
  if (t < 16384) w1b[t] = f2b_rne(w1[t]);
  else           w2b[t - 16384] = f2b_rne(w2[t - 16384]);
}

// ---- setup: spectral filter -> real 4x4 circular-conv kernel per channel ----
// irfft2(rfft2(y)*w) with ortho norm == circular conv with
// ker[d] = (1/16) sum_k Weff[k] e^{+2pi i k.d/4}, where Weff Hermitian-symmetrizes
// the DC/Nyquist columns (c2r drops their imaginary parts) and extends k2=3.
__global__ void setup_ker(const float* __restrict__ cw, float* __restrict__ ker) {
  int c = threadIdx.x;  // 0..63
  float cr[4][3], ci[4][3];
  for (int k1 = 0; k1 < 4; k1++)
    for (int k2 = 0; k2 < 3; k2++) {
      int idx = ((k1 * 3 + k2) * 64 + c) * 2;  // cweight (4,3,64,2)
      cr[k1][k2] = cw[idx];
      ci[k1][k2] = cw[idx + 1];
    }
  float Wr[4][4], Wi[4][4];
  for (int k1 = 0; k1 < 4; k1++) {
    int m = (4 - k1) & 3;
    Wr[k1][1] = cr[k1][1];                        Wi[k1][1] = ci[k1][1];
    Wr[k1][3] = cr[m][1];                         Wi[k1][3] = -ci[m][1];
    Wr[k1][0] = 0.5f * (cr[k1][0] + cr[m][0]);    Wi[k1][0] = 0.5f * (ci[k1][0] - ci[m][0]);
    Wr[k1][2] = 0.5f * (cr[k1][2] + cr[m][2]);    Wi[k1][2] = 0.5f * (ci[k1][2] - ci[m][2]);
  }
  const float ct[4] = {1.f, 0.f, -1.f, 0.f};
  const float st[4] = {0.f, 1.f, 0.f, -1.f};
  for (int d1 = 0; d1 < 4; d1++)
    for (int d2 = 0; d2 < 4; d2++) {
      float s = 0.f;
      for (int k1 = 0; k1 < 4; k1++)
        for (int k2 = 0; k2 < 4; k2++) {
          int t = (k1 * d1 + k2 * d2) & 3;
          s += Wr[k1][k2] * ct[t] - Wi[k1][k2] * st[t];  // Re(W * e^{i*2pi*t/4})
        }
      ker[c * 16 + d1 * 4 + d2] = s * (1.0f / 16.0f);
    }
}

// ---- main fused kernel ----
// Grid 2048 = b(8) x tile_row(64) x tile_colgrp(4). Block = 4 waves.
// Wave wv owns 4 windows (4x4 px) x 64 channels. Pixel index in a 16-row MFMA
// tile: m = hl*4 + wl  (one full window per tile) -> wave-local epilogue.
__global__ __launch_bounds__(256, 2) void fmffn_main(
    const float* __restrict__ x,
    const unsigned short* __restrict__ w1b,  // (256 hid, 64 c) bf16
    const float* __restrict__ b1,
    const unsigned short* __restrict__ w2b,  // (64 c, 256 hid) bf16
    const float* __restrict__ b2,
    const float* __restrict__ kerg,          // (64 c, 16) f32
    float* __restrict__ out) {
  // per-wave scratch: h (64 x 64 bf16, stride 72) / y (64 x 16 f32, stride 17)
  __shared__ unsigned short hbuf[4][64 * 72];

  const int tid  = threadIdx.x;
  const int wv   = tid >> 6;
  const int lane = tid & 63;
  const int q    = lane >> 4;
  const int n    = lane & 15;

  const int bid = blockIdx.x;
  const int tc  = bid & 3;
  const int tr  = (bid >> 2) & 63;
  const int b   = bid >> 8;

  // ---- A1 fragments: gather x (fp32, C-major) -> bf16. lane&15 = pixel m ----
  short8 a1[4][2];
  {
    const float* xb = x + (size_t)(b * 64) * 65536
                        + (size_t)((tr * 4 + (n >> 2)) * 256 + tc * 64 + (n & 3));
#pragma unroll
    for (int ti = 0; ti < 4; ti++) {
      const float* xp = xb + (wv * 4 + ti) * 4;
#pragma unroll
      for (int s = 0; s < 2; s++) {
        short8 v;
#pragma unroll
        for (int j = 0; j < 8; j++) {
          int c = s * 32 + q * 8 + j;
          v[j] = (short)f2b_rne(xp[(size_t)c * 65536]);
        }
        a1[ti][s] = v;
      }
    }
  }

  float b2v[4];
#pragma unroll
  for (int k = 0; k < 4; k++) b2v[k] = b2[k * 16 + n];

  floatx4 yacc[4][4];
#pragma unroll
  for (int i = 0; i < 4; i++)
#pragma unroll
    for (int j = 0; j < 4; j++)
      yacc[i][j] = (floatx4){0.f, 0.f, 0.f, 0.f};

  unsigned short* hl = &hbuf[wv][0];

#pragma unroll 1
  for (int chunk = 0; chunk < 4; chunk++) {
    // B1 fragments: w1b[hid][c], hid = chunk*64 + tj*16 + n
    short8 bw1[4][2];
#pragma unroll
    for (int tj = 0; tj < 4; tj++)
#pragma unroll
      for (int s = 0; s < 2; s++)
        bw1[tj][s] = *(const short8*)(w1b + (chunk * 64 + tj * 16 + n) * 64 + s * 32 + q * 8);

    float b1c[4];
#pragma unroll
    for (int tj = 0; tj < 4; tj++) b1c[tj] = b1[chunk * 64 + tj * 16 + n];

    floatx4 hacc[4][4];
#pragma unroll
    for (int i = 0; i < 4; i++)
#pragma unroll
      for (int j = 0; j < 4; j++)
        hacc[i][j] = (floatx4){0.f, 0.f, 0.f, 0.f};

#pragma unroll
    for (int s = 0; s < 2; s++)
#pragma unroll
      for (int tj = 0; tj < 4; tj++)
#pragma unroll
        for (int ti = 0; ti < 4; ti++)
          hacc[ti][tj] = __builtin_amdgcn_mfma_f32_16x16x32_bf16(
              a1[ti][s], bw1[tj][s], hacc[ti][tj], 0, 0, 0);

    // bias + exact GELU + cvt bf16 -> LDS (C-layout -> [p][hid] rows)
#pragma unroll
    for (int ti = 0; ti < 4; ti++)
#pragma unroll
      for (int tj = 0; tj < 4; tj++)
#pragma unroll
        for (int r = 0; r < 4; r++) {
          float v = hacc[ti][tj][r] + b1c[tj];
          float g = 0.5f * v * (1.0f + erff(v * 0.70710678118654752f));
          hl[(ti * 16 + q * 4 + r) * 72 + tj * 16 + n] = f2b_rne(g);
        }

    // B2 fragments: w2b[ch][hid], ch = tj*16 + n
    short8 bw2[4][2];
#pragma unroll
    for (int tj = 0; tj < 4; tj++)
#pragma unroll
      for (int s = 0; s < 2; s++)
        bw2[tj][s] = *(const short8*)(w2b + (tj * 16 + n) * 256 + chunk * 64 + s * 32 + q * 8);

    // A2 fragments from LDS: h[p = ti*16 + n][k = s*32 + q*8 ..+8]
    short8 a2[4][2];
#pragma unroll
    for (int ti = 0; ti < 4; ti++)
#pragma unroll
      for (int s = 0; s < 2; s++)
        a2[ti][s] = *(const short8*)(hl + (ti * 16 + n) * 72 + s * 32 + q * 8);

#pragma unroll
    for (int s = 0; s < 2; s++)
#pragma unroll
      for (int tj = 0; tj < 4; tj++)
#pragma unroll
        for (int ti = 0; ti < 4; ti++)
          yacc[ti][tj] = __builtin_amdgcn_mfma_f32_16x16x32_bf16(
              a2[ti][s], bw2[tj][s], yacc[ti][tj], 0, 0, 0);
  }

  // ---- epilogue: + b2, per-channel 4x4 circular conv, store (16 ch at a time) ----
  float* yl = (float*)hl;  // stride 17 f32
#pragma unroll 1
  for (int tj = 0; tj < 4; tj++) {
#pragma unroll
    for (int ti = 0; ti < 4; ti++)
#pragma unroll
      for (int r = 0; r < 4; r++)
        yl[(ti * 16 + q * 4 + r) * 17 + n] = yacc[ti][tj][r] + b2v[tj];

    // lane: window wi = q, channel = tj*16 + n
    float yv[16];
#pragma unroll
    for (int k = 0; k < 16; k++) yv[k] = yl[(q * 16 + k) * 17 + n];

    float kv[16];
    const float* kp = kerg + (tj * 16 + n) * 16;
#pragma unroll
    for (int t2 = 0; t2 < 16; t2++) kv[t2] = kp[t2];

    float* ob = out + (size_t)(b * 64 + tj * 16 + n) * 65536
                    + (tr * 4) * 256 + tc * 64 + (wv * 4 + q) * 4;
#pragma unroll
    for (int p1 = 0; p1 < 4; p1++) {
      floatx4 o;
#pragma unroll
      for (int p2 = 0; p2 < 4; p2++) {
        float s = 0.f;
#pragma unroll
        for (int q1 = 0; q1 < 4; q1++)
#pragma unroll
          for (int q2 = 0; q2 < 4; q2++)
            s += yv[q1 * 4 + q2] * kv[((p1 - q1) & 3) * 4 + ((p2 - q2) & 3)];
        o[p2] = s;
      }
      *(floatx4*)(ob + p1 * 256) = o;
    }
  }
}

extern "C" void kernel_launch(void* const* d_in, const int* in_sizes, int n_in,
                              void* d_out, int out_size, void* d_ws, size_t ws_size,
                              hipStream_t stream) {
  const float* x  = (const float*)d_in[0];
  const float* w1 = (const float*)d_in[1];
  const float* b1 = (const float*)d_in[2];
  const float* w2 = (const float*)d_in[3];
  const float* b2 = (const float*)d_in[4];
  const float* cw = (const float*)d_in[5];
  float* out = (float*)d_out;

  // ws layout: [0,32KiB) w1 bf16 | [32KiB,64KiB) w2 bf16 | [64KiB,+4KiB) ker f32
  unsigned short* w1b = (unsigned short*)d_ws;
  unsigned short* w2b = w1b + 16384;
  float* ker = (float*)((char*)d_ws + 65536);

  setup_weights<<<128, 256, 0, stream>>>(w1, w2, w1b, w2b);
  setup_ker<<<1, 64, 0, stream>>>(cw, ker);
  fmffn_main<<<2048, 256, 0, stream>>>(x, w1b, b1, w2b, b2, ker, out);
}

// Round 2
// 396.600 us; speedup vs baseline: 1.0262x; 1.0262x over previous
//
#include <hip/hip_runtime.h>
#include <hip/hip_bf16.h>
#include <math.h>

// FMFFN: x(8,64,256,256) -> 1x1conv(64->256) -> exact GELU -> 1x1conv(256->64)
//        -> per-channel 4x4-window spectral filter (== circular conv, setup_ker).
// R2: transposed gemm1 + permuted-K gemm2 (no h LDS round-trip), A&S-erf GELU,
//     coalesced staged stores.

typedef __attribute__((ext_vector_type(8))) short short8;
typedef __attribute__((ext_vector_type(4))) float floatx4;
typedef __attribute__((ext_vector_type(4))) unsigned int uintx4;

__device__ __forceinline__ unsigned rne_hi(float f) {
  unsigned u = __builtin_bit_cast(unsigned, f);
  return u + 0x7fffu + ((u >> 16) & 1u);
}
__device__ __forceinline__ unsigned short f2b_rne(float f) {
  return (unsigned short)(rne_hi(f) >> 16);
}
__device__ __forceinline__ unsigned pack_b(float lo, float hi) {
  return (rne_hi(lo) >> 16) | (rne_hi(hi) & 0xffff0000u);
}
// exact-GELU via A&S 7.1.26 erf approx (|err|<=1.5e-7): ~15 VALU ops
__device__ __forceinline__ float gelu_f(float v) {
  float av = fabsf(v);
  float a  = av * 0.70710678118654752f;
  float t  = __builtin_amdgcn_rcpf(fmaf(a, 0.3275911f, 1.0f));
  float p  = t * fmaf(t, fmaf(t, fmaf(t, fmaf(t, 1.061405429f, -1.453152027f),
                                      1.421413741f), -0.284496736f), 0.254829592f);
  float e  = __expf(-a * a);
  float er = fmaf(-p, e, 1.0f);          // erf(a) in [0,1]
  return fmaf(0.5f * av, er, 0.5f * v);  // 0.5v(1+sign(v)erf(|v|/sqrt2))
}

// ---- setup: cast w1 (256x64) and w2 (64x256) to bf16 ----
__global__ void setup_weights(const float* __restrict__ w1, const float* __restrict__ w2,
                              unsigned short* __restrict__ w1b, unsigned short* __restrict__ w2b) {
  int t = blockIdx.x * 256 + threadIdx.x;  // 0..32767
  if (t < 16384) w1b[t] = f2b_rne(w1[t]);
  else           w2b[t - 16384] = f2b_rne(w2[t - 16384]);
}

// ---- setup: spectral filter -> real 4x4 circular-conv kernel per channel ----
__global__ void setup_ker(const float* __restrict__ cw, float* __restrict__ ker) {
  int c = threadIdx.x;  // 0..63
  float cr[4][3], ci[4][3];
  for (int k1 = 0; k1 < 4; k1++)
    for (int k2 = 0; k2 < 3; k2++) {
      int idx = ((k1 * 3 + k2) * 64 + c) * 2;  // cweight (4,3,64,2)
      cr[k1][k2] = cw[idx];
      ci[k1][k2] = cw[idx + 1];
    }
  float Wr[4][4], Wi[4][4];
  for (int k1 = 0; k1 < 4; k1++) {
    int m = (4 - k1) & 3;
    Wr[k1][1] = cr[k1][1];                        Wi[k1][1] = ci[k1][1];
    Wr[k1][3] = cr[m][1];                         Wi[k1][3] = -ci[m][1];
    Wr[k1][0] = 0.5f * (cr[k1][0] + cr[m][0]);    Wi[k1][0] = 0.5f * (ci[k1][0] - ci[m][0]);
    Wr[k1][2] = 0.5f * (cr[k1][2] + cr[m][2]);    Wi[k1][2] = 0.5f * (ci[k1][2] - ci[m][2]);
  }
  const float ct[4] = {1.f, 0.f, -1.f, 0.f};
  const float st[4] = {0.f, 1.f, 0.f, -1.f};
  for (int d1 = 0; d1 < 4; d1++)
    for (int d2 = 0; d2 < 4; d2++) {
      float s = 0.f;
      for (int k1 = 0; k1 < 4; k1++)
        for (int k2 = 0; k2 < 4; k2++) {
          int t = (k1 * d1 + k2 * d2) & 3;
          s += Wr[k1][k2] * ct[t] - Wi[k1][k2] * st[t];
        }
      ker[c * 16 + d1 * 4 + d2] = s * (1.0f / 16.0f);
    }
}

// ---- main fused kernel ----
// Grid 2048 = b(8) x tr(64 row-groups of 4) x tc(4 col-groups of 64).
// Wave wv owns row tr*4+wv; pixel tile ti = 16 consecutive cols (tc*64+ti*16+n).
// gemm1 (transposed): hacc[ti][tjh] = w1frag x xfrag -> h keyed (hid=q*4+r, px=n).
// gemm2 (permuted K): a2 = in-lane repack of GELU(hacc); w2 B-frag gathered with
// the matching hid permutation phi(q*8+j) = T*16+q*4+j. Full-rate 16x16x32 MFMA.
__global__ __launch_bounds__(256, 3) void fmffn_main(
    const float* __restrict__ x,
    const unsigned short* __restrict__ w1b,  // (256 hid, 64 c) bf16
    const float* __restrict__ b1,
    const unsigned short* __restrict__ w2b,  // (64 c, 256 hid) bf16
    const float* __restrict__ b2,
    const float* __restrict__ kerg,          // (64 c, 16) f32
    float* __restrict__ out) {
  // staging: y f32 [16 ch][4 rows][64 cols], strides ch=276, row=68 (pad: 16B
  // aligned + conflict-free for b128 write/read patterns). 17.25 KiB.
  __shared__ float stage[4416];

  const int tid  = threadIdx.x;
  const int wv   = tid >> 6;
  const int lane = tid & 63;
  const int q    = lane >> 4;
  const int n    = lane & 15;

  const int bid = blockIdx.x;
  const int tc  = bid & 3;
  const int tr  = (bid >> 2) & 63;
  const int b   = bid >> 8;

  // ---- x B-frags: lane(q,n) holds x[ch=s*32+q*8+j][pixel n of tile ti] ----
  // per-instruction: 16 lanes read 64B contiguous (cols tc*64+ti*16 .. +15)
  short8 xf[4][2];
  {
    const float* xp = x + (size_t)(b * 64) * 65536
                        + (size_t)((tr * 4 + wv) * 256 + tc * 64 + n);
#pragma unroll
    for (int ti = 0; ti < 4; ti++)
#pragma unroll
      for (int s = 0; s < 2; s++) {
        short8 v;
#pragma unroll
        for (int j = 0; j < 8; j++) {
          int c = s * 32 + q * 8 + j;
          v[j] = (short)f2b_rne(xp[(size_t)c * 65536 + ti * 16]);
        }
        xf[ti][s] = v;
      }
  }

  floatx4 yacc[4][4];
#pragma unroll
  for (int i = 0; i < 4; i++)
#pragma unroll
    for (int j = 0; j < 4; j++)
      yacc[i][j] = (floatx4){0.f, 0.f, 0.f, 0.f};

#pragma unroll 1
  for (int chunk = 0; chunk < 4; chunk++) {
    // w1 A-frags: A[m=hid][k=ch]: lane(q,n): w1b[(chunk*64+tjh*16+n)*64 + s*32+q*8 ..+8]
    short8 wf[4][2];
#pragma unroll
    for (int tjh = 0; tjh < 4; tjh++)
#pragma unroll
      for (int s = 0; s < 2; s++)
        wf[tjh][s] = *(const short8*)(w1b + (chunk * 64 + tjh * 16 + n) * 64 + s * 32 + q * 8);

    floatx4 hacc[4][4];
#pragma unroll
    for (int i = 0; i < 4; i++)
#pragma unroll
      for (int j = 0; j < 4; j++)
        hacc[i][j] = (floatx4){0.f, 0.f, 0.f, 0.f};

#pragma unroll
    for (int s = 0; s < 2; s++)
#pragma unroll
      for (int tjh = 0; tjh < 4; tjh++)
#pragma unroll
        for (int ti = 0; ti < 4; ti++)
          hacc[ti][tjh] = __builtin_amdgcn_mfma_f32_16x16x32_bf16(
              wf[tjh][s], xf[ti][s], hacc[ti][tjh], 0, 0, 0);

    // bias: b1[chunk*64 + tjh*16 + q*4 + r] (16B-aligned vector load)
    floatx4 b1v[4];
#pragma unroll
    for (int tjh = 0; tjh < 4; tjh++)
      b1v[tjh] = *(const floatx4*)(b1 + chunk * 64 + tjh * 16 + q * 4);

    // GELU + bf16 pack, in-lane. pk[ti][tjh] = {r0r1, r2r3}
    unsigned pk[4][4][2];
#pragma unroll
    for (int ti = 0; ti < 4; ti++)
#pragma unroll
      for (int tjh = 0; tjh < 4; tjh++) {
        float g0 = gelu_f(hacc[ti][tjh][0] + b1v[tjh][0]);
        float g1 = gelu_f(hacc[ti][tjh][1] + b1v[tjh][1]);
        float g2 = gelu_f(hacc[ti][tjh][2] + b1v[tjh][2]);
        float g3 = gelu_f(hacc[ti][tjh][3] + b1v[tjh][3]);
        pk[ti][tjh][0] = pack_b(g0, g1);
        pk[ti][tjh][1] = pack_b(g2, g3);
      }

    // gemm2: two K=32 MFMAs per chunk; hid permutation phi(q*8+j):
    //   j=0..3 -> kc*32 + q*4 + j ; j=4..7 -> kc*32 + 16 + q*4 + (j-4)
#pragma unroll
    for (int kc = 0; kc < 2; kc++) {
      short8 a2[4];
#pragma unroll
      for (int ti = 0; ti < 4; ti++) {
        uintx4 u = (uintx4){pk[ti][2 * kc][0], pk[ti][2 * kc][1],
                            pk[ti][2 * kc + 1][0], pk[ti][2 * kc + 1][1]};
        a2[ti] = __builtin_bit_cast(short8, u);
      }
      short8 bw2[4];
#pragma unroll
      for (int tjc = 0; tjc < 4; tjc++) {
        const unsigned short* wp = w2b + (tjc * 16 + n) * 256 + chunk * 64 + kc * 32 + q * 4;
        unsigned lo0 = *(const unsigned*)(wp);
        unsigned lo1 = *(const unsigned*)(wp + 2);
        unsigned hi0 = *(const unsigned*)(wp + 16);
        unsigned hi1 = *(const unsigned*)(wp + 18);
        uintx4 u = (uintx4){lo0, lo1, hi0, hi1};
        bw2[tjc] = __builtin_bit_cast(short8, u);
      }
#pragma unroll
      for (int tjc = 0; tjc < 4; tjc++)
#pragma unroll
        for (int ti = 0; ti < 4; ti++)
          yacc[ti][tjc] = __builtin_amdgcn_mfma_f32_16x16x32_bf16(
              a2[ti], bw2[tjc], yacc[ti][tjc], 0, 0, 0);
    }
  }

  // ---- epilogue: +b2, stage 16ch x 4row x 64col in LDS, conv, coalesced store ----
  float b2v[4];
#pragma unroll
  for (int k = 0; k < 4; k++) b2v[k] = b2[k * 16 + n];

  const int ch16 = tid >> 4;   // 0..15 (conv/store phase)
  const int sub  = tid & 15;   // window / col4 index

#pragma unroll 1
  for (int tjc = 0; tjc < 4; tjc++) {
    __syncthreads();  // WAR vs previous round's readers
    // yacc[ti][tjc] lane(q,n): pixel row=wv, col=ti*16+q*4+r, ch=n
#pragma unroll
    for (int ti = 0; ti < 4; ti++) {
      floatx4 val = yacc[ti][tjc];
      val[0] += b2v[tjc]; val[1] += b2v[tjc]; val[2] += b2v[tjc]; val[3] += b2v[tjc];
      *(floatx4*)&stage[n * 276 + wv * 68 + ti * 16 + q * 4] = val;
    }
    __syncthreads();

    // conv + store: thread -> (ch16, window sub); out cols sub*4..+3, rows 0..3
    float kv[16];
    const float* kp = kerg + (tjc * 16 + ch16) * 16;
#pragma unroll
    for (int t = 0; t < 16; t++) kv[t] = kp[t];

    floatx4 yv[4];
#pragma unroll
    for (int q1 = 0; q1 < 4; q1++)
      yv[q1] = *(const floatx4*)&stage[ch16 * 276 + q1 * 68 + sub * 4];

    float* ob = out + (size_t)(b * 64 + tjc * 16 + ch16) * 65536
                    + (size_t)((tr * 4) * 256 + tc * 64 + sub * 4);
#pragma unroll
    for (int p1 = 0; p1 < 4; p1++) {
      floatx4 o;
#pragma unroll
      for (int p2 = 0; p2 < 4; p2++) {
        float s = 0.f;
#pragma unroll
        for (int q1 = 0; q1 < 4; q1++)
#pragma unroll
          for (int q2 = 0; q2 < 4; q2++)
            s += yv[q1][q2] * kv[((p1 - q1) & 3) * 4 + ((p2 - q2) & 3)];
        o[p2] = s;
      }
      *(floatx4*)(ob + p1 * 256) = o;  // 16 lanes => 256B contiguous, line-aligned
    }
  }
}

extern "C" void kernel_launch(void* const* d_in, const int* in_sizes, int n_in,
                              void* d_out, int out_size, void* d_ws, size_t ws_size,
                              hipStream_t stream) {
  const float* x  = (const float*)d_in[0];
  const float* w1 = (const float*)d_in[1];
  const float* b1 = (const float*)d_in[2];
  const float* w2 = (const float*)d_in[3];
  const float* b2 = (const float*)d_in[4];
  const float* cw = (const float*)d_in[5];
  float* out = (float*)d_out;

  unsigned short* w1b = (unsigned short*)d_ws;
  unsigned short* w2b = w1b + 16384;
  float* ker = (float*)((char*)d_ws + 65536);

  setup_weights<<<128, 256, 0, stream>>>(w1, w2, w1b, w2b);
  setup_ker<<<1, 64, 0, stream>>>(cw, ker);
  fmffn_main<<<2048, 256, 0, stream>>>(x, w1b, b1, w2b, b2, ker, out);
}

// Round 3
// 352.326 us; speedup vs baseline: 1.1552x; 1.1257x over previous
//
#include <hip/hip_runtime.h>
#include <hip/hip_bf16.h>
#include <math.h>

// FMFFN: x(8,64,256,256) -> 1x1conv(64->256) -> exact GELU -> 1x1conv(256->64)
//        -> per-channel 4x4-window spectral filter (== circular conv, setup_ker).
// R3: weights pre-permuted into MFMA-fragment lane order (coalesced dwordx4,
//     kills the 64x L2 request amplification of R1/R2), nontemporal x/out.

typedef __attribute__((ext_vector_type(8))) short short8;
typedef __attribute__((ext_vector_type(4))) float floatx4;
typedef __attribute__((ext_vector_type(4))) unsigned int uintx4;

__device__ __forceinline__ unsigned rne_hi(float f) {
  unsigned u = __builtin_bit_cast(unsigned, f);
  return u + 0x7fffu + ((u >> 16) & 1u);
}
__device__ __forceinline__ unsigned short f2b_rne(float f) {
  return (unsigned short)(rne_hi(f) >> 16);
}
__device__ __forceinline__ unsigned pack_b(float lo, float hi) {
  return (rne_hi(lo) >> 16) | (rne_hi(hi) & 0xffff0000u);
}
// exact-GELU via A&S 7.1.26 erf approx (|err|<=1.5e-7): ~15 VALU ops
__device__ __forceinline__ float gelu_f(float v) {
  float av = fabsf(v);
  float a  = av * 0.70710678118654752f;
  float t  = __builtin_amdgcn_rcpf(fmaf(a, 0.3275911f, 1.0f));
  float p  = t * fmaf(t, fmaf(t, fmaf(t, fmaf(t, 1.061405429f, -1.453152027f),
                                      1.421413741f), -0.284496736f), 0.254829592f);
  float e  = __expf(-a * a);
  float er = fmaf(-p, e, 1.0f);          // erf(a) in [0,1]
  return fmaf(0.5f * av, er, 0.5f * v);  // 0.5v(1+sign(v)erf(|v|/sqrt2))
}

// ---- setup: permute w1/w2 into MFMA-fragment lane order, cast bf16 ----
// w1f[((chunk*4+tjh)*2+s)*64+lane][j] = w1[(chunk*64+tjh*16+n)*64 + s*32+q*8+j]
// w2f[((chunk*2+kc)*4+tjc)*64+lane][j] = w2[(tjc*16+n)*256 + chunk*64+kc*32+ho],
//   ho = j<4 ? q*4+j : 16+q*4+(j-4)   (the permuted-K gemm2 gather)
__global__ void setup_frag(const float* __restrict__ w1, const float* __restrict__ w2,
                           unsigned short* __restrict__ w1f, unsigned short* __restrict__ w2f) {
  int t = blockIdx.x * 256 + threadIdx.x;  // 0..32767
  int g = t & 16383;
  int j = g & 7;
  int u = g >> 3;
  int lane = u & 63, v = u >> 6;
  int q = lane >> 4, n = lane & 15;
  if (t < 16384) {
    int s = v & 1, tjh = (v >> 1) & 3, chunk = v >> 3;
    w1f[g] = f2b_rne(w1[(chunk * 64 + tjh * 16 + n) * 64 + s * 32 + q * 8 + j]);
  } else {
    int tjc = v & 3, kc = (v >> 2) & 1, chunk = v >> 3;
    int ho = (j < 4) ? (q * 4 + j) : (16 + q * 4 + (j - 4));
    w2f[g] = f2b_rne(w2[(tjc * 16 + n) * 256 + chunk * 64 + kc * 32 + ho]);
  }
}

// ---- setup: spectral filter -> real 4x4 circular-conv kernel per channel ----
__global__ void setup_ker(const float* __restrict__ cw, float* __restrict__ ker) {
  int c = threadIdx.x;  // 0..63
  float cr[4][3], ci[4][3];
  for (int k1 = 0; k1 < 4; k1++)
    for (int k2 = 0; k2 < 3; k2++) {
      int idx = ((k1 * 3 + k2) * 64 + c) * 2;  // cweight (4,3,64,2)
      cr[k1][k2] = cw[idx];
      ci[k1][k2] = cw[idx + 1];
    }
  float Wr[4][4], Wi[4][4];
  for (int k1 = 0; k1 < 4; k1++) {
    int m = (4 - k1) & 3;
    Wr[k1][1] = cr[k1][1];                        Wi[k1][1] = ci[k1][1];
    Wr[k1][3] = cr[m][1];                         Wi[k1][3] = -ci[m][1];
    Wr[k1][0] = 0.5f * (cr[k1][0] + cr[m][0]);    Wi[k1][0] = 0.5f * (ci[k1][0] - ci[m][0]);
    Wr[k1][2] = 0.5f * (cr[k1][2] + cr[m][2]);    Wi[k1][2] = 0.5f * (ci[k1][2] - ci[m][2]);
  }
  const float ct[4] = {1.f, 0.f, -1.f, 0.f};
  const float st[4] = {0.f, 1.f, 0.f, -1.f};
  for (int d1 = 0; d1 < 4; d1++)
    for (int d2 = 0; d2 < 4; d2++) {
      float s = 0.f;
      for (int k1 = 0; k1 < 4; k1++)
        for (int k2 = 0; k2 < 4; k2++) {
          int t = (k1 * d1 + k2 * d2) & 3;
          s += Wr[k1][k2] * ct[t] - Wi[k1][k2] * st[t];
        }
      ker[c * 16 + d1 * 4 + d2] = s * (1.0f / 16.0f);
    }
}

// ---- main fused kernel ----
// Grid 2048 = b(8) x tr(64 row-groups of 4) x tc(4 col-groups of 64).
// Wave wv owns row tr*4+wv; pixel tile ti = 16 consecutive cols (tc*64+ti*16+n).
// gemm1 (transposed): hacc = w1frag x xfrag -> h keyed (hid=q*4+r, px=n).
// gemm2 (permuted K): a2 = in-lane repack of GELU(hacc); w2 frag pre-permuted.
__global__ __launch_bounds__(256, 3) void fmffn_main(
    const float* __restrict__ x,
    const unsigned short* __restrict__ w1f,  // fragment-ordered bf16 (32KB)
    const float* __restrict__ b1,
    const unsigned short* __restrict__ w2f,  // fragment-ordered bf16 (32KB)
    const float* __restrict__ b2,
    const float* __restrict__ kerg,          // (64 c, 16) f32
    float* __restrict__ out) {
  // staging: y f32 [16 ch][4 rows][64 cols], strides ch=276, row=68. 17.25 KiB.
  __shared__ float stage[4416];

  const int tid  = threadIdx.x;
  const int wv   = tid >> 6;
  const int lane = tid & 63;
  const int q    = lane >> 4;
  const int n    = lane & 15;

  const int bid = blockIdx.x;
  const int tc  = bid & 3;
  const int tr  = (bid >> 2) & 63;
  const int b   = bid >> 8;

  // ---- x B-frags: lane(q,n) holds x[ch=s*32+q*8+j][pixel n of tile ti] ----
  short8 xf[4][2];
  {
    const float* xp = x + (size_t)(b * 64) * 65536
                        + (size_t)((tr * 4 + wv) * 256 + tc * 64 + n);
#pragma unroll
    for (int ti = 0; ti < 4; ti++)
#pragma unroll
      for (int s = 0; s < 2; s++) {
        short8 v;
#pragma unroll
        for (int j = 0; j < 8; j++) {
          int c = s * 32 + q * 8 + j;
          v[j] = (short)f2b_rne(__builtin_nontemporal_load(xp + (size_t)c * 65536 + ti * 16));
        }
        xf[ti][s] = v;
      }
  }

  floatx4 yacc[4][4];
#pragma unroll
  for (int i = 0; i < 4; i++)
#pragma unroll
    for (int j = 0; j < 4; j++)
      yacc[i][j] = (floatx4){0.f, 0.f, 0.f, 0.f};

#pragma unroll 1
  for (int chunk = 0; chunk < 4; chunk++) {
    // w1 A-frags: contiguous dwordx4, 1KB/wave-instruction, L2-resident
    short8 wf[4][2];
#pragma unroll
    for (int tjh = 0; tjh < 4; tjh++)
#pragma unroll
      for (int s = 0; s < 2; s++)
        wf[tjh][s] = *(const short8*)(w1f + ((((chunk * 4 + tjh) * 2 + s) * 64 + lane) << 3));

    floatx4 hacc[4][4];
#pragma unroll
    for (int i = 0; i < 4; i++)
#pragma unroll
      for (int j = 0; j < 4; j++)
        hacc[i][j] = (floatx4){0.f, 0.f, 0.f, 0.f};

#pragma unroll
    for (int s = 0; s < 2; s++)
#pragma unroll
      for (int tjh = 0; tjh < 4; tjh++)
#pragma unroll
        for (int ti = 0; ti < 4; ti++)
          hacc[ti][tjh] = __builtin_amdgcn_mfma_f32_16x16x32_bf16(
              wf[tjh][s], xf[ti][s], hacc[ti][tjh], 0, 0, 0);

    // bias: b1[chunk*64 + tjh*16 + q*4 + r]
    floatx4 b1v[4];
#pragma unroll
    for (int tjh = 0; tjh < 4; tjh++)
      b1v[tjh] = *(const floatx4*)(b1 + chunk * 64 + tjh * 16 + q * 4);

    // GELU + bf16 pack, in-lane
    unsigned pk[4][4][2];
#pragma unroll
    for (int ti = 0; ti < 4; ti++)
#pragma unroll
      for (int tjh = 0; tjh < 4; tjh++) {
        float g0 = gelu_f(hacc[ti][tjh][0] + b1v[tjh][0]);
        float g1 = gelu_f(hacc[ti][tjh][1] + b1v[tjh][1]);
        float g2 = gelu_f(hacc[ti][tjh][2] + b1v[tjh][2]);
        float g3 = gelu_f(hacc[ti][tjh][3] + b1v[tjh][3]);
        pk[ti][tjh][0] = pack_b(g0, g1);
        pk[ti][tjh][1] = pack_b(g2, g3);
      }

    // gemm2: two K=32 MFMAs per chunk, w2 frags pre-permuted
#pragma unroll
    for (int kc = 0; kc < 2; kc++) {
      short8 a2[4];
#pragma unroll
      for (int ti = 0; ti < 4; ti++) {
        uintx4 u = (uintx4){pk[ti][2 * kc][0], pk[ti][2 * kc][1],
                            pk[ti][2 * kc + 1][0], pk[ti][2 * kc + 1][1]};
        a2[ti] = __builtin_bit_cast(short8, u);
      }
      short8 bw2[4];
#pragma unroll
      for (int tjc = 0; tjc < 4; tjc++)
        bw2[tjc] = *(const short8*)(w2f + ((((chunk * 2 + kc) * 4 + tjc) * 64 + lane) << 3));
#pragma unroll
      for (int tjc = 0; tjc < 4; tjc++)
#pragma unroll
        for (int ti = 0; ti < 4; ti++)
          yacc[ti][tjc] = __builtin_amdgcn_mfma_f32_16x16x32_bf16(
              a2[ti], bw2[tjc], yacc[ti][tjc], 0, 0, 0);
    }
  }

  // ---- epilogue: +b2, stage 16ch x 4row x 64col in LDS, conv, coalesced store ----
  float b2v[4];
#pragma unroll
  for (int k = 0; k < 4; k++) b2v[k] = b2[k * 16 + n];

  const int ch16 = tid >> 4;   // 0..15 (conv/store phase)
  const int sub  = tid & 15;   // window / col4 index

#pragma unroll 1
  for (int tjc = 0; tjc < 4; tjc++) {
    __syncthreads();  // WAR vs previous round's readers
    // yacc[ti][tjc] lane(q,n): pixel row=wv, col=ti*16+q*4+r, ch=n
#pragma unroll
    for (int ti = 0; ti < 4; ti++) {
      floatx4 val = yacc[ti][tjc];
      val[0] += b2v[tjc]; val[1] += b2v[tjc]; val[2] += b2v[tjc]; val[3] += b2v[tjc];
      *(floatx4*)&stage[n * 276 + wv * 68 + ti * 16 + q * 4] = val;
    }
    __syncthreads();

    // conv + store: thread -> (ch16, window sub); out cols sub*4..+3, rows 0..3
    float kv[16];
    const float* kp = kerg + (tjc * 16 + ch16) * 16;
#pragma unroll
    for (int t = 0; t < 16; t++) kv[t] = kp[t];

    floatx4 yv[4];
#pragma unroll
    for (int q1 = 0; q1 < 4; q1++)
      yv[q1] = *(const floatx4*)&stage[ch16 * 276 + q1 * 68 + sub * 4];

    float* ob = out + (size_t)(b * 64 + tjc * 16 + ch16) * 65536
                    + (size_t)((tr * 4) * 256 + tc * 64 + sub * 4);
#pragma unroll
    for (int p1 = 0; p1 < 4; p1++) {
      floatx4 o;
#pragma unroll
      for (int p2 = 0; p2 < 4; p2++) {
        float s = 0.f;
#pragma unroll
        for (int q1 = 0; q1 < 4; q1++)
#pragma unroll
          for (int q2 = 0; q2 < 4; q2++)
            s += yv[q1][q2] * kv[((p1 - q1) & 3) * 4 + ((p2 - q2) & 3)];
        o[p2] = s;
      }
      __builtin_nontemporal_store(o, (floatx4*)(ob + p1 * 256));  // 256B/16 lanes
    }
  }
}

extern "C" void kernel_launch(void* const* d_in, const int* in_sizes, int n_in,
                              void* d_out, int out_size, void* d_ws, size_t ws_size,
                              hipStream_t stream) {
  const float* x  = (const float*)d_in[0];
  const float* w1 = (const float*)d_in[1];
  const float* b1 = (const float*)d_in[2];
  const float* w2 = (const float*)d_in[3];
  const float* b2 = (const float*)d_in[4];
  const float* cw = (const float*)d_in[5];
  float* out = (float*)d_out;

  unsigned short* w1f = (unsigned short*)d_ws;
  unsigned short* w2f = w1f + 16384;
  float* ker = (float*)((char*)d_ws + 65536);

  setup_frag<<<128, 256, 0, stream>>>(w1, w2, w1f, w2f);
  setup_ker<<<1, 64, 0, stream>>>(cw, ker);
  fmffn_main<<<2048, 256, 0, stream>>>(x, w1f, b1, w2f, b2, ker, out);
}